// Round 1
// baseline (353.164 us; speedup 1.0000x reference)
//
#include <hip/hip_runtime.h>
#include <math.h>

#define N_NODES 50000
#define N_EDGES 800000
#define IN_CH 256
#define OUT_CH 64
#define NEG_SLOPE 0.2f

// ---------------------------------------------------------------------------
// Kernel A: feature = x @ W^T + b  (M=50000, K=256, N=64)
// Fused epilogue: e0[n] = feature[n]·att[:,0], e1[n] = feature[n]·att[:,1],
//                 denom[n] = exp(leakyrelu(e0+e1))   (self-loop term)
// Block: 256 threads -> 64 rows x 64 cols tile, 4x4 micro-tile per thread.
// LDS tiles stored [k][m] (transposed) with pad 68 so both fragment reads are
// ds_read_b128 and ~conflict-free.
// ---------------------------------------------------------------------------
__global__ __launch_bounds__(256) void k_gemm(
    const float* __restrict__ x, const float* __restrict__ W,
    const float* __restrict__ bias, const float* __restrict__ att,
    float* __restrict__ feature, float* __restrict__ e0,
    float* __restrict__ e1, float* __restrict__ denom)
{
    constexpr int LDP = 68;                 // 64 + 4 pad (keeps 16B align, breaks pow2 stride)
    __shared__ float xst[64][LDP];          // [k][row]
    __shared__ float wt[64][LDP];           // [k][col]

    const int t  = threadIdx.x;
    const int tx = t & 15;                  // col group (4 cols)
    const int ty = t >> 4;                  // row group (4 rows)
    const int row0 = blockIdx.x * 64;

    float acc[4][4] = {};

    for (int kc = 0; kc < IN_CH; kc += 64) {
        __syncthreads();                    // prev compute done before overwrite
        #pragma unroll
        for (int i = 0; i < 4; ++i) {
            int quad = t + i * 256;         // 0..1023
            int r    = quad >> 4;           // 0..63  (x-row / W-row==out-col)
            int kq   = quad & 15;           // 0..15  (k quad)
            // x tile (guarded; tail rows -> 0)
            float4 v = make_float4(0.f, 0.f, 0.f, 0.f);
            int gr = row0 + r;
            if (gr < N_NODES)
                v = *reinterpret_cast<const float4*>(&x[gr * IN_CH + kc + kq * 4]);
            xst[kq * 4 + 0][r] = v.x;
            xst[kq * 4 + 1][r] = v.y;
            xst[kq * 4 + 2][r] = v.z;
            xst[kq * 4 + 3][r] = v.w;
            // W tile (64 rows exactly, no guard)
            float4 w4 = *reinterpret_cast<const float4*>(&W[r * IN_CH + kc + kq * 4]);
            wt[kq * 4 + 0][r] = w4.x;
            wt[kq * 4 + 1][r] = w4.y;
            wt[kq * 4 + 2][r] = w4.z;
            wt[kq * 4 + 3][r] = w4.w;
        }
        __syncthreads();

        #pragma unroll 8
        for (int k = 0; k < 64; ++k) {
            float4 a  = *reinterpret_cast<const float4*>(&xst[k][ty * 4]);
            float4 bb = *reinterpret_cast<const float4*>(&wt[k][tx * 4]);
            float av[4] = {a.x, a.y, a.z, a.w};
            float bv[4] = {bb.x, bb.y, bb.z, bb.w};
            #pragma unroll
            for (int i = 0; i < 4; ++i)
                #pragma unroll
                for (int j = 0; j < 4; ++j)
                    acc[i][j] += av[i] * bv[j];
        }
    }

    // epilogue: bias, store feature, per-row att partials
    float att0[4], att1[4], bv[4];
    #pragma unroll
    for (int j = 0; j < 4; ++j) {
        int c = tx * 4 + j;
        att0[j] = att[c * 2 + 0];
        att1[j] = att[c * 2 + 1];
        bv[j]   = bias[c];
    }

    float p0[4], p1[4];
    #pragma unroll
    for (int i = 0; i < 4; ++i) {
        int gr = row0 + ty * 4 + i;
        float f0 = acc[i][0] + bv[0];
        float f1 = acc[i][1] + bv[1];
        float f2 = acc[i][2] + bv[2];
        float f3 = acc[i][3] + bv[3];
        p0[i] = f0 * att0[0] + f1 * att0[1] + f2 * att0[2] + f3 * att0[3];
        p1[i] = f0 * att1[0] + f1 * att1[1] + f2 * att1[2] + f3 * att1[3];
        if (gr < N_NODES) {
            *reinterpret_cast<float4*>(&feature[gr * OUT_CH + tx * 4]) =
                make_float4(f0, f1, f2, f3);
        }
    }

    // reduce partials across the 16 tx lanes (stay within wave: masks 1..8)
    #pragma unroll
    for (int m = 1; m < 16; m <<= 1) {
        #pragma unroll
        for (int i = 0; i < 4; ++i) {
            p0[i] += __shfl_xor(p0[i], m, 64);
            p1[i] += __shfl_xor(p1[i], m, 64);
        }
    }
    if (tx == 0) {
        #pragma unroll
        for (int i = 0; i < 4; ++i) {
            int gr = row0 + ty * 4 + i;
            if (gr < N_NODES) {
                float z = p0[i] + p1[i];
                float lr = z > 0.f ? z : NEG_SLOPE * z;
                e0[gr] = p0[i];
                e1[gr] = p1[i];
                denom[gr] = __expf(z);  // placeholder overwritten below
                denom[gr] = expf(lr);
            }
        }
    }
}

// ---------------------------------------------------------------------------
// Kernel B: per-edge exp(leakyrelu(logit)), accumulate denom[tar]
// ---------------------------------------------------------------------------
__global__ __launch_bounds__(256) void k_edge(
    const int* __restrict__ ei, const float* __restrict__ e0,
    const float* __restrict__ e1, float* __restrict__ denom,
    float* __restrict__ exp_edge)
{
    int e = blockIdx.x * blockDim.x + threadIdx.x;
    if (e >= N_EDGES) return;
    int tnode = ei[e];
    int snode = ei[N_EDGES + e];
    float z  = e0[tnode] + e1[snode];
    float lr = z > 0.f ? z : NEG_SLOPE * z;
    float w  = expf(lr);
    exp_edge[e] = w;
    atomicAdd(&denom[tnode], w);
}

// ---------------------------------------------------------------------------
// Kernel C: out[n] = (exp_self/denom) * feature[n]   (initializes d_out fully)
// thread per (node, 4-channel quad)
// ---------------------------------------------------------------------------
__global__ __launch_bounds__(256) void k_self(
    const float* __restrict__ e0, const float* __restrict__ e1,
    const float* __restrict__ denom, const float* __restrict__ feature,
    float* __restrict__ out)
{
    int idx = blockIdx.x * blockDim.x + threadIdx.x;
    if (idx >= N_NODES * 16) return;
    int n = idx >> 4;
    int q = idx & 15;
    float z  = e0[n] + e1[n];
    float lr = z > 0.f ? z : NEG_SLOPE * z;
    float a  = expf(lr) / denom[n];
    float4 f = *reinterpret_cast<const float4*>(&feature[n * OUT_CH + q * 4]);
    *reinterpret_cast<float4*>(&out[n * OUT_CH + q * 4]) =
        make_float4(a * f.x, a * f.y, a * f.z, a * f.w);
}

// ---------------------------------------------------------------------------
// Kernel D: scatter messages — one wave per edge, lane = channel
// out[tar][c] += (exp_edge/denom[tar]) * feature[src][c]
// ---------------------------------------------------------------------------
__global__ __launch_bounds__(256) void k_scatter(
    const int* __restrict__ ei, const float* __restrict__ exp_edge,
    const float* __restrict__ denom, const float* __restrict__ feature,
    float* __restrict__ out)
{
    int idx = blockIdx.x * blockDim.x + threadIdx.x;   // < E*64 = 51.2M
    int e = idx >> 6;
    int c = idx & 63;
    if (e >= N_EDGES) return;
    int tnode = ei[e];
    int snode = ei[N_EDGES + e];
    float alpha = exp_edge[e] / denom[tnode];
    atomicAdd(&out[tnode * OUT_CH + c], alpha * feature[snode * OUT_CH + c]);
}

// ---------------------------------------------------------------------------
extern "C" void kernel_launch(void* const* d_in, const int* in_sizes, int n_in,
                              void* d_out, int out_size, void* d_ws, size_t ws_size,
                              hipStream_t stream)
{
    const float* x    = (const float*)d_in[0];
    const int*   ei   = (const int*)d_in[1];
    const float* W    = (const float*)d_in[2];
    const float* bias = (const float*)d_in[3];
    const float* att  = (const float*)d_in[4];
    float* out = (float*)d_out;

    // workspace layout (floats): feature[N*64] | e0[N] | e1[N] | denom[N] | exp_edge[E]
    float* ws       = (float*)d_ws;
    float* feature  = ws;
    float* e0       = feature + (size_t)N_NODES * OUT_CH;
    float* e1       = e0 + N_NODES;
    float* denom    = e1 + N_NODES;
    float* exp_edge = denom + N_NODES;

    dim3 blk(256);

    // A: GEMM + epilogue
    k_gemm<<<dim3((N_NODES + 63) / 64), blk, 0, stream>>>(
        x, W, bias, att, feature, e0, e1, denom);

    // B: edge logits -> exp, denom accumulation
    k_edge<<<dim3((N_EDGES + 255) / 256), blk, 0, stream>>>(
        ei, e0, e1, denom, exp_edge);

    // C: self term (initializes out)
    k_self<<<dim3((N_NODES * 16 + 255) / 256), blk, 0, stream>>>(
        e0, e1, denom, feature, out);

    // D: edge message scatter
    k_scatter<<<dim3((N_EDGES * 64) / 256), blk, 0, stream>>>(
        ei, exp_edge, denom, feature, out);
}